// Round 16
// baseline (286.345 us; speedup 1.0000x reference)
//
#include <hip/hip_runtime.h>
#include <hip/hip_fp16.h>

#define NEG_SLOPE 0.2f

static inline int cdiv(long long a, long long b) { return (int)((a + b - 1) / b); }

typedef _Float16 f16x8 __attribute__((ext_vector_type(8)));
typedef float f32x4 __attribute__((ext_vector_type(4)));

union h8u {
    f16x8   v;
    __half2 h2[4];
};

__device__ __forceinline__ void load_sd(const void* ei_raw, int is64, int e, int E_,
                                        int& s, int& d)
{
    if (is64) {
        const long long* p = (const long long*)ei_raw;
        s = (int)p[e];
        d = (int)p[E_ + e];
    } else {
        const int* p = (const int*)ei_raw;
        s = p[e];
        d = p[E_ + e];
    }
}

// ---------------------------------------------------------------------------
// PREP: int64 probe (block 0), deg zero-init, W fp32->fp16 transposes.
// ---------------------------------------------------------------------------
__global__ __launch_bounds__(256) void prep_kernel(
    const void* __restrict__ ei, int E_, int n, int* __restrict__ flag,
    int* __restrict__ deg,
    const float* __restrict__ W1, __half* __restrict__ Wt1,
    const float* __restrict__ W2, __half* __restrict__ Wt2,
    const float* __restrict__ W3, __half* __restrict__ Wt3)
{
    int idx = blockIdx.x * 256 + threadIdx.x;

    if (blockIdx.x == 0) {
        __shared__ int bad;
        if (threadIdx.x == 0) bad = 0;
        __syncthreads();
        const long long* e64 = (const long long*)ei;
        int cnt = E_ < 512 ? E_ : 512;
        bool ok = true;
        for (int i = threadIdx.x; i < cnt; i += 256) {
            long long v = e64[i];
            if (v < 0 || v >= n) ok = false;
        }
        if (!ok) atomicAdd(&bad, 1);
        __syncthreads();
        if (threadIdx.x == 0) *flag = (bad == 0) ? 1 : 0;
    }

    if (idx < n) deg[idx] = 0;

    if (idx < 128 * 32) {
        int k = idx / 32, c = idx % 32;
        Wt1[c * 128 + k] = __float2half(W1[idx]);
    }
    if (idx < 32 * 128) {
        int k = idx / 128, c = idx % 128;
        Wt2[c * 32 + k] = __float2half(W2[idx]);
    }
    if (idx < 128 * 128) {
        int k = idx / 128, c = idx % 128;
        Wt3[c * 128 + k] = __float2half(W3[idx]);
    }
}

// ---------------------------------------------------------------------------
// FUSED dispatch: layer-1 MFMA GEMM (blocks < gemmBlocks) || hist (rest).
// The two paths are fully independent (gemm1 needs only x/W1; hist needs
// prep's flag+deg) — block-split fusion gives concurrency without streams.
// ---------------------------------------------------------------------------
__global__ __launch_bounds__(256) void gemm1_hist_kernel(
    const float* __restrict__ x, const __half* __restrict__ Wt1,
    const float* __restrict__ att_s, const float* __restrict__ att_d,
    __half* __restrict__ h, float* __restrict__ a_s, float* __restrict__ a_d,
    int n, int gemmBlocks,
    const void* __restrict__ ei, const int* __restrict__ flag,
    int* __restrict__ deg, unsigned short* __restrict__ s16,
    unsigned short* __restrict__ d16, unsigned short* __restrict__ r16, int E_)
{
    // gemm<K=128,NOUT=32> constants
    constexpr int KC = 32, NT = 2, XP = 40, HP = 40, C = 8;
    __shared__ _Float16 Xs[64 * XP];
    __shared__ _Float16 Ws[32 * XP];
    __shared__ _Float16 Hs[64 * HP];
    __shared__ float As[32], Ad[32];

    const int tid = threadIdx.x;

    if (blockIdx.x >= gemmBlocks) {
        // ---------------- hist path ----------------
        int base = (blockIdx.x - gemmBlocks) * 1024 + tid;
        int is64 = *flag;
        int sj[4], dj[4], rj[4];
        bool v[4];
#pragma unroll
        for (int j = 0; j < 4; j++) {
            int e = base + j * 256;
            v[j] = e < E_;
            if (v[j]) load_sd(ei, is64, e, E_, sj[j], dj[j]);
        }
#pragma unroll
        for (int j = 0; j < 4; j++) {
            int e = base + j * 256;
            if (v[j]) {
                s16[e] = (unsigned short)sj[j];
                d16[e] = (unsigned short)dj[j];
            }
        }
#pragma unroll
        for (int j = 0; j < 4; j++) {
            if (v[j]) rj[j] = atomicAdd(deg + dj[j], 1);
        }
#pragma unroll
        for (int j = 0; j < 4; j++) {
            int e = base + j * 256;
            if (v[j]) r16[e] = (unsigned short)rj[j];
        }
        return;
    }

    // ---------------- gemm1 path (K=128, NOUT=32, A from fp32) ----------------
    const int nb   = blockIdx.x * 64;
    const int wave = tid >> 6, lane = tid & 63;
    const int m16  = lane & 15, quad = lane >> 4;

    if (tid < 32) { As[tid] = att_s[tid]; Ad[tid] = att_d[tid]; }

    f32x4 acc[NT];
#pragma unroll
    for (int t = 0; t < NT; t++) acc[t] = (f32x4){0.f, 0.f, 0.f, 0.f};

    for (int kc = 0; kc < 128; kc += KC) {
        {
            int node = tid >> 2, seg = tid & 3;
            int gn = nb + node;
            f16x8 v = {0, 0, 0, 0, 0, 0, 0, 0};
            if (gn < n) {
                const float4* p = (const float4*)(x + (size_t)gn * 128 + kc + seg * 8);
                float4 a = p[0], b = p[1];
                v = (f16x8){(_Float16)a.x, (_Float16)a.y, (_Float16)a.z, (_Float16)a.w,
                            (_Float16)b.x, (_Float16)b.y, (_Float16)b.z, (_Float16)b.w};
            }
            *(f16x8*)&Xs[node * XP + seg * 8] = v;
        }
        if (tid < 32 * 4) {
            int col = tid >> 2, seg = tid & 3;
            *(f16x8*)&Ws[col * XP + seg * 8] =
                *(const f16x8*)(Wt1 + (size_t)col * 128 + kc + seg * 8);
        }
        __syncthreads();

        f16x8 a = *(const f16x8*)&Xs[(wave * 16 + m16) * XP + quad * 8];
#pragma unroll
        for (int t = 0; t < NT; t++) {
            f16x8 b = *(const f16x8*)&Ws[(t * 16 + m16) * XP + quad * 8];
            acc[t] = __builtin_amdgcn_mfma_f32_16x16x32_f16(a, b, acc[t], 0, 0, 0);
        }
        __syncthreads();
    }

#pragma unroll
    for (int t = 0; t < NT; t++) {
#pragma unroll
        for (int r = 0; r < 4; r++) {
            int row = wave * 16 + quad * 4 + r;
            Hs[row * HP + t * 16 + m16] = (_Float16)acc[t][r];
        }
    }
    __syncthreads();

    if (tid < 64 * 4) {
        int row = tid >> 2, seg = tid & 3;
        int gn = nb + row;
        if (gn < n)
            *(f16x8*)(h + (size_t)gn * 32 + seg * 8) = *(const f16x8*)&Hs[row * HP + seg * 8];
    }

    {
        int node = tid >> 2, head = tid & 3;
        int gn = nb + node;
        const _Float16* hr = &Hs[node * HP + head * C];
        float s1 = 0.f, s2 = 0.f;
#pragma unroll
        for (int c = 0; c < C; c++) {
            float v = (float)hr[c];
            s1 += v * As[head * C + c];
            s2 += v * Ad[head * C + c];
        }
        if (gn < n) {
            a_s[gn * 4 + head] = s1;
            a_d[gn * 4 + head] = s2;
        }
    }
}

// ---------------------------------------------------------------------------
// CSR scan + scatter (Round-12 structure, unchanged).
// ---------------------------------------------------------------------------
__device__ __forceinline__ int wave_incl_scan(int v)
{
    int lane = threadIdx.x & 63;
#pragma unroll
    for (int off = 1; off < 64; off <<= 1) {
        int t = __shfl_up(v, off);
        if (lane >= off) v += t;
    }
    return v;
}

__global__ __launch_bounds__(1024) void scan_part_kernel(const int* __restrict__ deg,
                                                         int* __restrict__ start,
                                                         int* __restrict__ bsum, int n)
{
    __shared__ int wsum[16];
    int i = blockIdx.x * 1024 + threadIdx.x;
    int wid = threadIdx.x >> 6, lane = threadIdx.x & 63;
    int v = (i < n) ? deg[i] : 0;
    int incl = wave_incl_scan(v);
    if (lane == 63) wsum[wid] = incl;
    __syncthreads();
    if (wid == 0) {
        int w = (lane < 16) ? wsum[lane] : 0;
        w = wave_incl_scan(w);
        if (lane < 16) wsum[lane] = w;
    }
    __syncthreads();
    int excl = incl - v + (wid ? wsum[wid - 1] : 0);
    if (i < n) start[i] = excl;
    if (threadIdx.x == 1023) bsum[blockIdx.x] = wsum[15];
}

__global__ __launch_bounds__(1024) void scan_add_kernel(const int* __restrict__ deg,
                                                        const int* __restrict__ bsum,
                                                        int* __restrict__ start, int n)
{
    __shared__ int off_sh;
    if (threadIdx.x == 0) {
        int s = 0;
        for (int j = 0; j < blockIdx.x; j++) s += bsum[j];
        off_sh = s;
    }
    __syncthreads();
    int i = blockIdx.x * 1024 + threadIdx.x;
    if (i >= n) return;
    int v = start[i] + off_sh;
    start[i] = v;
    if (i == n - 1) start[n] = v + deg[i];
}

__global__ __launch_bounds__(256) void scatter_kernel(
    const unsigned short* __restrict__ s16, const unsigned short* __restrict__ d16,
    const unsigned short* __restrict__ r16, const int* __restrict__ start,
    unsigned short* __restrict__ sorted_src, int E_)
{
    int base = blockIdx.x * 1024 + threadIdx.x;
    int sj[4], dj[4], rj[4];
    bool v[4];
#pragma unroll
    for (int j = 0; j < 4; j++) {
        int e = base + j * 256;
        v[j] = e < E_;
        sj[j] = v[j] ? (int)s16[e] : 0;
        dj[j] = v[j] ? (int)d16[e] : 0;
        rj[j] = v[j] ? (int)r16[e] : 0;
    }
    int pj[4];
#pragma unroll
    for (int j = 0; j < 4; j++) {
        if (v[j]) pj[j] = start[dj[j]] + rj[j];
    }
#pragma unroll
    for (int j = 0; j < 4; j++) {
        if (v[j])
            __builtin_nontemporal_store((unsigned short)sj[j], sorted_src + pj[j]);
    }
}

// ---------------------------------------------------------------------------
// FUSED agg32 -> gemm2. Block = 64 nodes.
// Phase A: single-sweep softmax-agg of layer-1 (F=32, 4 lanes/node,
// 8-deep pipelined 16 B gathers); bias1+ELU; fp16 result straight into the
// GEMM's Xs tile (no x2h global round-trip).
// Phase B: MFMA gemm<K=32,NOUT=128> from LDS + attention epilogue.
// ---------------------------------------------------------------------------
__global__ __launch_bounds__(256) void agg32_gemm2_kernel(
    const int* __restrict__ start, const unsigned short* __restrict__ ss,
    const __half* __restrict__ h_in, const float* __restrict__ a_s,
    const float* __restrict__ a_d, const float* __restrict__ b1,
    const __half* __restrict__ Wt2, const float* __restrict__ as2,
    const float* __restrict__ ad2, __half* __restrict__ h_out,
    float* __restrict__ a_s2, float* __restrict__ a_d2, int n)
{
    constexpr int XP = 40, HP = 136, NT = 8;
    __shared__ _Float16 Xs[64 * XP];
    __shared__ _Float16 Ws[128 * XP];
    __shared__ _Float16 Hs[64 * HP];
    __shared__ float As[128], Ad[128];

    const int tid = threadIdx.x;
    const int nb  = blockIdx.x * 64;

    if (tid < 128) { As[tid] = as2[tid]; Ad[tid] = ad2[tid]; }

    // ---- Phase A ----
    {
        int local = tid >> 2;   // node 0..63
        int q     = tid & 3;    // lane = head; owns features 8q..8q+7
        int node  = nb + local;
        bool active = node < n;
        int s0 = 0, s1 = 0;
        if (active) { s0 = start[node]; s1 = start[node + 1]; }
        float adh = active ? a_d[node * 4 + q] : 0.f;
        const f16x8* __restrict__ h8 = (const f16x8*)h_in + q;

        float acc[8];
#pragma unroll
        for (int j = 0; j < 8; j++) acc[j] = 0.f;
        float sm = 0.f;

        int i = s0;
        for (; i + 8 <= s1; i += 8) {
            int   sj[8];
            float ej[8];
            h8u   rj[8];
#pragma unroll
            for (int j = 0; j < 8; j++) sj[j] = (int)ss[i + j];
#pragma unroll
            for (int j = 0; j < 8; j++) ej[j] = a_s[sj[j] * 4 + q];
#pragma unroll
            for (int j = 0; j < 8; j++) rj[j].v = h8[(size_t)sj[j] * 4];
#pragma unroll
            for (int j = 0; j < 8; j++) {
                float e = ej[j] + adh;
                e = e > 0.f ? e : NEG_SLOPE * e;
                float p = __expf(e);
                sm += p;
#pragma unroll
                for (int k = 0; k < 4; k++) {
                    float2 f = __half22float2(rj[j].h2[k]);
                    acc[2 * k]     += f.x * p;
                    acc[2 * k + 1] += f.y * p;
                }
            }
        }
        for (; i < s1; i++) {
            int s = (int)ss[i];
            float e = a_s[s * 4 + q] + adh;
            e = e > 0.f ? e : NEG_SLOPE * e;
            float p = __expf(e);
            sm += p;
            h8u u; u.v = h8[(size_t)s * 4];
#pragma unroll
            for (int k = 0; k < 4; k++) {
                float2 f = __half22float2(u.h2[k]);
                acc[2 * k]     += f.x * p;
                acc[2 * k + 1] += f.y * p;
            }
        }

        h8u o;
        if (active) {
            float inv = 1.f / (sm + 1e-16f);
#pragma unroll
            for (int k = 0; k < 4; k++) {
                float vx = acc[2 * k] * inv     + b1[q * 8 + 2 * k];
                float vy = acc[2 * k + 1] * inv + b1[q * 8 + 2 * k + 1];
                vx = vx > 0.f ? vx : (__expf(vx) - 1.f);
                vy = vy > 0.f ? vy : (__expf(vy) - 1.f);
                o.h2[k] = __floats2half2_rn(vx, vy);
            }
        } else {
            o.v = (f16x8){0, 0, 0, 0, 0, 0, 0, 0};
        }
        *(f16x8*)&Xs[local * XP + q * 8] = o.v;
    }

    // ---- Phase B: gemm K=32, NOUT=128 ----
    if (tid < 128 * 4 / 2) {  // 256 threads cover 512 f16x8 units in 2 iters
        // handled by loop below instead
    }
    for (int u = tid; u < 128 * 4; u += 256) {
        int col = u >> 2, seg = u & 3;
        *(f16x8*)&Ws[col * XP + seg * 8] =
            *(const f16x8*)(Wt2 + (size_t)col * 32 + seg * 8);
    }
    __syncthreads();

    const int wave = tid >> 6, lane = tid & 63;
    const int m16  = lane & 15, quad = lane >> 4;

    f32x4 acc[NT];
#pragma unroll
    for (int t = 0; t < NT; t++) acc[t] = (f32x4){0.f, 0.f, 0.f, 0.f};

    f16x8 a = *(const f16x8*)&Xs[(wave * 16 + m16) * XP + quad * 8];
#pragma unroll
    for (int t = 0; t < NT; t++) {
        f16x8 b = *(const f16x8*)&Ws[(t * 16 + m16) * XP + quad * 8];
        acc[t] = __builtin_amdgcn_mfma_f32_16x16x32_f16(a, b, acc[t], 0, 0, 0);
    }
    __syncthreads();

#pragma unroll
    for (int t = 0; t < NT; t++) {
#pragma unroll
        for (int r = 0; r < 4; r++) {
            int row = wave * 16 + quad * 4 + r;
            Hs[row * HP + t * 16 + m16] = (_Float16)acc[t][r];
        }
    }
    __syncthreads();

    for (int u = tid; u < 64 * 16; u += 256) {
        int row = u >> 4, seg = u & 15;
        int gn = nb + row;
        if (gn < n)
            *(f16x8*)(h_out + (size_t)gn * 128 + seg * 8) =
                *(const f16x8*)&Hs[row * HP + seg * 8];
    }

    {
        int node = tid >> 2, head = tid & 3;
        int gn = nb + node;
        const _Float16* hr = &Hs[node * HP + head * 32];
        float s1 = 0.f, s2 = 0.f;
#pragma unroll 4
        for (int c = 0; c < 32; c++) {
            float v = (float)hr[c];
            s1 += v * As[head * 32 + c];
            s2 += v * Ad[head * 32 + c];
        }
        if (gn < n) {
            a_s2[gn * 4 + head] = s1;
            a_d2[gn * 4 + head] = s2;
        }
    }
}

// ---------------------------------------------------------------------------
// FUSED agg128 -> gemm3. Block = 64 nodes.
// Phase A: single-sweep softmax-agg of layer-2 (F=128, 16 lanes/node,
// 16 node-groups x 4 iterations); bias2+ELU; fp16 into Xs (full 64x128 A).
// Phase B: MFMA gemm<K=128,NOUT=128> (Ws staged per 32-chunk; A persistent
// in LDS) + attention epilogue (as3/ad3).
// ---------------------------------------------------------------------------
__global__ __launch_bounds__(256) void agg128_gemm3_kernel(
    const int* __restrict__ start, const unsigned short* __restrict__ ss,
    const __half* __restrict__ h_in, const float* __restrict__ a_s,
    const float* __restrict__ a_d, const float* __restrict__ b2,
    const __half* __restrict__ Wt3, const float* __restrict__ as3,
    const float* __restrict__ ad3, __half* __restrict__ h_out,
    float* __restrict__ a_s3, float* __restrict__ a_d3, int n)
{
    constexpr int XAP = 136, XP = 40, HP = 136, NT = 8;
    __shared__ _Float16 Xs[64 * XAP];
    __shared__ _Float16 Ws[128 * XP];
    __shared__ _Float16 Hs[64 * HP];
    __shared__ float As[128], Ad[128];

    const int tid = threadIdx.x;
    const int nb  = blockIdx.x * 64;

    if (tid < 128) { As[tid] = as3[tid]; Ad[tid] = ad3[tid]; }

    // ---- Phase A: 16 lanes/node, 4 iterations over 64 nodes ----
    {
        int grp = tid >> 4;   // 0..15
        int q   = tid & 15;   // owns features 8q..8q+7
        int head = q >> 2;
        const f16x8* __restrict__ h8 = (const f16x8*)h_in + q;

        for (int it = 0; it < 4; it++) {
            int local = it * 16 + grp;
            int node  = nb + local;
            bool active = node < n;
            int s0 = 0, s1 = 0;
            if (active) { s0 = start[node]; s1 = start[node + 1]; }
            float adh = active ? a_d[node * 4 + head] : 0.f;

            float acc[8];
#pragma unroll
            for (int j = 0; j < 8; j++) acc[j] = 0.f;
            float sm = 0.f;

            int i = s0;
            for (; i + 8 <= s1; i += 8) {
                int   sj[8];
                float ej[8];
                h8u   rj[8];
#pragma unroll
                for (int j = 0; j < 8; j++) sj[j] = (int)ss[i + j];
#pragma unroll
                for (int j = 0; j < 8; j++) ej[j] = a_s[sj[j] * 4 + head];
#pragma unroll
                for (int j = 0; j < 8; j++) rj[j].v = h8[(size_t)sj[j] * 16];
#pragma unroll
                for (int j = 0; j < 8; j++) {
                    float e = ej[j] + adh;
                    e = e > 0.f ? e : NEG_SLOPE * e;
                    float p = __expf(e);
                    sm += p;
#pragma unroll
                    for (int k = 0; k < 4; k++) {
                        float2 f = __half22float2(rj[j].h2[k]);
                        acc[2 * k]     += f.x * p;
                        acc[2 * k + 1] += f.y * p;
                    }
                }
            }
            for (; i < s1; i++) {
                int s = (int)ss[i];
                float e = a_s[s * 4 + head] + adh;
                e = e > 0.f ? e : NEG_SLOPE * e;
                float p = __expf(e);
                sm += p;
                h8u u; u.v = h8[(size_t)s * 16];
#pragma unroll
                for (int k = 0; k < 4; k++) {
                    float2 f = __half22float2(u.h2[k]);
                    acc[2 * k]     += f.x * p;
                    acc[2 * k + 1] += f.y * p;
                }
            }

            h8u o;
            if (active) {
                float inv = 1.f / (sm + 1e-16f);
#pragma unroll
                for (int k = 0; k < 4; k++) {
                    float vx = acc[2 * k] * inv     + b2[q * 8 + 2 * k];
                    float vy = acc[2 * k + 1] * inv + b2[q * 8 + 2 * k + 1];
                    vx = vx > 0.f ? vx : (__expf(vx) - 1.f);
                    vy = vy > 0.f ? vy : (__expf(vy) - 1.f);
                    o.h2[k] = __floats2half2_rn(vx, vy);
                }
            } else {
                o.v = (f16x8){0, 0, 0, 0, 0, 0, 0, 0};
            }
            *(f16x8*)&Xs[local * XAP + q * 8] = o.v;
        }
    }

    // ---- Phase B: gemm K=128, NOUT=128 (A persistent in Xs) ----
    const int wave = tid >> 6, lane = tid & 63;
    const int m16  = lane & 15, quad = lane >> 4;

    f32x4 acc[NT];
#pragma unroll
    for (int t = 0; t < NT; t++) acc[t] = (f32x4){0.f, 0.f, 0.f, 0.f};

    for (int kc = 0; kc < 128; kc += 32) {
        for (int u = tid; u < 128 * 4; u += 256) {
            int col = u >> 2, seg = u & 3;
            *(f16x8*)&Ws[col * XP + seg * 8] =
                *(const f16x8*)(Wt3 + (size_t)col * 128 + kc + seg * 8);
        }
        __syncthreads();

        f16x8 a = *(const f16x8*)&Xs[(wave * 16 + m16) * XAP + kc + quad * 8];
#pragma unroll
        for (int t = 0; t < NT; t++) {
            f16x8 b = *(const f16x8*)&Ws[(t * 16 + m16) * XP + quad * 8];
            acc[t] = __builtin_amdgcn_mfma_f32_16x16x32_f16(a, b, acc[t], 0, 0, 0);
        }
        __syncthreads();
    }

#pragma unroll
    for (int t = 0; t < NT; t++) {
#pragma unroll
        for (int r = 0; r < 4; r++) {
            int row = wave * 16 + quad * 4 + r;
            Hs[row * HP + t * 16 + m16] = (_Float16)acc[t][r];
        }
    }
    __syncthreads();

    for (int u = tid; u < 64 * 16; u += 256) {
        int row = u >> 4, seg = u & 15;
        int gn = nb + row;
        if (gn < n)
            *(f16x8*)(h_out + (size_t)gn * 128 + seg * 8) =
                *(const f16x8*)&Hs[row * HP + seg * 8];
    }

    {
        int node = tid >> 2, head = tid & 3;
        int gn = nb + node;
        const _Float16* hr = &Hs[node * HP + head * 32];
        float s1 = 0.f, s2 = 0.f;
#pragma unroll 4
        for (int c = 0; c < 32; c++) {
            float v = (float)hr[c];
            s1 += v * As[head * 32 + c];
            s2 += v * Ad[head * 32 + c];
        }
        if (gn < n) {
            a_s3[gn * 4 + head] = s1;
            a_d3[gn * 4 + head] = s2;
        }
    }
}

// ---------------------------------------------------------------------------
// FINAL single-sweep agg, F = 128, head-mean + bias -> fp32 (Round-15).
// 16 thr/node, 16 nodes/block.
// ---------------------------------------------------------------------------
__global__ __launch_bounds__(256) void gat_agg_final_kernel(
    const int* __restrict__ start, const unsigned short* __restrict__ ss,
    const __half* __restrict__ h, const float* __restrict__ a_s,
    const float* __restrict__ a_d, const float* __restrict__ bias,
    float* __restrict__ out, int n)
{
    int local = threadIdx.x >> 4;
    int q     = threadIdx.x & 15;
    int node  = blockIdx.x * 16 + local;
    bool active = node < n;
    int s0 = 0, s1 = 0;
    if (active) { s0 = start[node]; s1 = start[node + 1]; }
    int head = q >> 2;
    float adh = active ? a_d[node * 4 + head] : 0.f;
    const f16x8* __restrict__ h8 = (const f16x8*)h + q;

    float acc[8];
#pragma unroll
    for (int j = 0; j < 8; j++) acc[j] = 0.f;
    float sm = 0.f;

    int i = s0;
    for (; i + 8 <= s1; i += 8) {
        int   sj[8];
        float ej[8];
        h8u   rj[8];
#pragma unroll
        for (int j = 0; j < 8; j++) sj[j] = (int)ss[i + j];
#pragma unroll
        for (int j = 0; j < 8; j++) ej[j] = a_s[sj[j] * 4 + head];
#pragma unroll
        for (int j = 0; j < 8; j++) rj[j].v = h8[(size_t)sj[j] * 16];
#pragma unroll
        for (int j = 0; j < 8; j++) {
            float e = ej[j] + adh;
            e = e > 0.f ? e : NEG_SLOPE * e;
            float p = __expf(e);
            sm += p;
#pragma unroll
            for (int k = 0; k < 4; k++) {
                float2 f = __half22float2(rj[j].h2[k]);
                acc[2 * k]     += f.x * p;
                acc[2 * k + 1] += f.y * p;
            }
        }
    }
    for (; i < s1; i++) {
        int s = (int)ss[i];
        float e = a_s[s * 4 + head] + adh;
        e = e > 0.f ? e : NEG_SLOPE * e;
        float p = __expf(e);
        sm += p;
        h8u u; u.v = h8[(size_t)s * 16];
#pragma unroll
        for (int k = 0; k < 4; k++) {
            float2 f = __half22float2(u.h2[k]);
            acc[2 * k]     += f.x * p;
            acc[2 * k + 1] += f.y * p;
        }
    }

    float inv = 1.f / (sm + 1e-16f);
#pragma unroll
    for (int j = 0; j < 8; j++) acc[j] *= inv;

    __shared__ float sh[16][132];
#pragma unroll
    for (int j = 0; j < 8; j++) sh[local][q * 8 + j] = acc[j];
    __syncthreads();
    if (q < 4 && active) {
        float r[8];
#pragma unroll
        for (int j = 0; j < 8; j++) {
            int c = q * 8 + j;
            r[j] = 0.25f * (sh[local][c] + sh[local][32 + c] + sh[local][64 + c] +
                            sh[local][96 + c]) + bias[c];
        }
        float4* o4 = (float4*)(out + (size_t)node * 32 + q * 8);
        o4[0] = make_float4(r[0], r[1], r[2], r[3]);
        o4[1] = make_float4(r[4], r[5], r[6], r[7]);
    }
}

// ---------------------------------------------------------------------------

extern "C" void kernel_launch(void* const* d_in, const int* in_sizes, int n_in,
                              void* d_out, int out_size, void* d_ws, size_t ws_size,
                              hipStream_t stream)
{
    const float* x   = (const float*)d_in[0];
    const void*  ei  = d_in[1];
    const float* W1  = (const float*)d_in[2];
    const float* as1 = (const float*)d_in[3];
    const float* ad1 = (const float*)d_in[4];
    const float* b1  = (const float*)d_in[5];
    const float* W2  = (const float*)d_in[6];
    const float* as2 = (const float*)d_in[7];
    const float* ad2 = (const float*)d_in[8];
    const float* b2  = (const float*)d_in[9];
    const float* W3  = (const float*)d_in[10];
    const float* as3 = (const float*)d_in[11];
    const float* ad3 = (const float*)d_in[12];
    const float* b3  = (const float*)d_in[13];
    float* out = (float*)d_out;

    const int N_ = in_sizes[0] / 128;
    const int E_ = in_sizes[1] / 2;

    char* ws = (char*)d_ws;
    size_t off = 0;
    auto alloc = [&](size_t nbytes) -> void* {
        void* p = ws + off;
        off += (nbytes + 255) & ~(size_t)255;
        return p;
    };
    __half* hA         = (__half*)alloc((size_t)N_ * 128 * 2);  // layer1 (F=32), layer3 (F=128)
    __half* hB         = (__half*)alloc((size_t)N_ * 128 * 2);  // layer2 (F=128)
    __half* Wt1        = (__half*)alloc(128 * 32 * 2);
    __half* Wt2        = (__half*)alloc(32 * 128 * 2);
    __half* Wt3        = (__half*)alloc(128 * 128 * 2);
    float* asA         = (float*)alloc((size_t)N_ * 4 * 4);
    float* adA         = (float*)alloc((size_t)N_ * 4 * 4);
    float* asB         = (float*)alloc((size_t)N_ * 4 * 4);
    float* adB         = (float*)alloc((size_t)N_ * 4 * 4);
    int*   deg         = (int*)alloc((size_t)N_ * 4);
    int*   start       = (int*)alloc((size_t)(N_ + 1) * 4);
    unsigned short* sorted_src = (unsigned short*)alloc((size_t)E_ * 2);
    unsigned short* s16        = (unsigned short*)alloc((size_t)E_ * 2);
    unsigned short* d16        = (unsigned short*)alloc((size_t)E_ * 2);
    unsigned short* r16        = (unsigned short*)alloc((size_t)E_ * 2);
    int*   bsum        = (int*)alloc(4096);
    int*   flag        = (int*)alloc(256);

    const int gN16 = cdiv(N_, 16);
    const int gN64 = cdiv(N_, 64);
    const int gHist = cdiv(E_, 1024);
    const int nSB  = cdiv(N_, 1024);
    int prepWork = N_ > 128 * 128 ? N_ : 128 * 128;

    // ---- Prep, then [gemm1 || hist] in one dispatch ----
    prep_kernel<<<cdiv(prepWork, 256), 256, 0, stream>>>(ei, E_, N_, flag, deg,
                                                         W1, Wt1, W2, Wt2, W3, Wt3);
    gemm1_hist_kernel<<<gN64 + gHist, 256, 0, stream>>>(
        x, Wt1, as1, ad1, hA, asA, adA, N_, gN64,
        ei, flag, deg, s16, d16, r16, E_);
    scan_part_kernel<<<nSB, 1024, 0, stream>>>(deg, start, bsum, N_);
    scan_add_kernel<<<nSB, 1024, 0, stream>>>(deg, bsum, start, N_);
    scatter_kernel<<<cdiv(E_, 1024), 256, 0, stream>>>(s16, d16, r16, start,
                                                       sorted_src, E_);

    // ---- Layer 1 agg -> layer 2 gemm (fused) ----
    agg32_gemm2_kernel<<<gN64, 256, 0, stream>>>(start, sorted_src, hA, asA, adA, b1,
                                                 Wt2, as2, ad2, hB, asB, adB, N_);

    // ---- Layer 2 agg -> layer 3 gemm (fused) ----
    agg128_gemm3_kernel<<<gN64, 256, 0, stream>>>(start, sorted_src, hB, asB, adB, b2,
                                                  Wt3, as3, ad3, hA, asA, adA, N_);

    // ---- Layer 3 final agg (head-mean + bias) ----
    gat_agg_final_kernel<<<gN16, 256, 0, stream>>>(start, sorted_src, hA, asA, adA, b3,
                                                   out, N_);
}

// Round 17
// 277.332 us; speedup vs baseline: 1.0325x; 1.0325x over previous
//
#include <hip/hip_runtime.h>
#include <hip/hip_fp16.h>

#define NEG_SLOPE 0.2f

static inline int cdiv(long long a, long long b) { return (int)((a + b - 1) / b); }

typedef _Float16 f16x8 __attribute__((ext_vector_type(8)));
typedef float f32x4 __attribute__((ext_vector_type(4)));

union h8u {
    f16x8   v;
    __half2 h2[4];
};

__device__ __forceinline__ void load_sd(const void* ei_raw, int is64, int e, int E_,
                                        int& s, int& d)
{
    if (is64) {
        const long long* p = (const long long*)ei_raw;
        s = (int)p[e];
        d = (int)p[E_ + e];
    } else {
        const int* p = (const int*)ei_raw;
        s = p[e];
        d = p[E_ + e];
    }
}

// ---------------------------------------------------------------------------
// PREP: int64 probe (block 0), deg zero-init, W fp32->fp16 transposes.
// ---------------------------------------------------------------------------
__global__ __launch_bounds__(256) void prep_kernel(
    const void* __restrict__ ei, int E_, int n, int* __restrict__ flag,
    int* __restrict__ deg,
    const float* __restrict__ W1, __half* __restrict__ Wt1,
    const float* __restrict__ W2, __half* __restrict__ Wt2,
    const float* __restrict__ W3, __half* __restrict__ Wt3)
{
    int idx = blockIdx.x * 256 + threadIdx.x;

    if (blockIdx.x == 0) {
        __shared__ int bad;
        if (threadIdx.x == 0) bad = 0;
        __syncthreads();
        const long long* e64 = (const long long*)ei;
        int cnt = E_ < 512 ? E_ : 512;
        bool ok = true;
        for (int i = threadIdx.x; i < cnt; i += 256) {
            long long v = e64[i];
            if (v < 0 || v >= n) ok = false;
        }
        if (!ok) atomicAdd(&bad, 1);
        __syncthreads();
        if (threadIdx.x == 0) *flag = (bad == 0) ? 1 : 0;
    }

    if (idx < n) deg[idx] = 0;

    if (idx < 128 * 32) {
        int k = idx / 32, c = idx % 32;
        Wt1[c * 128 + k] = __float2half(W1[idx]);
    }
    if (idx < 32 * 128) {
        int k = idx / 128, c = idx % 128;
        Wt2[c * 32 + k] = __float2half(W2[idx]);
    }
    if (idx < 128 * 128) {
        int k = idx / 128, c = idx % 128;
        Wt3[c * 128 + k] = __float2half(W3[idx]);
    }
}

// ---------------------------------------------------------------------------
// FUSED dispatch: layer-1 MFMA GEMM (blocks < gemmBlocks) || hist (rest).
// Independent work; hist's atomic-latency time hides under the GEMM.
// (Round-16 lesson: do NOT fuse gathers into LDS-heavy kernels — but this
// block-split fusion adds no LDS to the hist path and keeps both at their
// natural occupancy.)
// ---------------------------------------------------------------------------
__global__ __launch_bounds__(256) void gemm1_hist_kernel(
    const float* __restrict__ x, const __half* __restrict__ Wt1,
    const float* __restrict__ att_s, const float* __restrict__ att_d,
    __half* __restrict__ h, float* __restrict__ a_s, float* __restrict__ a_d,
    int n, int gemmBlocks,
    const void* __restrict__ ei, const int* __restrict__ flag,
    int* __restrict__ deg, unsigned short* __restrict__ s16,
    unsigned short* __restrict__ d16, unsigned short* __restrict__ r16, int E_)
{
    constexpr int KC = 32, NT = 2, XP = 40, HP = 40, C = 8;
    __shared__ _Float16 Xs[64 * XP];
    __shared__ _Float16 Ws[32 * XP];
    __shared__ _Float16 Hs[64 * HP];
    __shared__ float As[32], Ad[32];

    const int tid = threadIdx.x;

    if (blockIdx.x >= gemmBlocks) {
        // ---------------- hist path ----------------
        int base = (blockIdx.x - gemmBlocks) * 1024 + tid;
        int is64 = *flag;
        int sj[4], dj[4], rj[4];
        bool v[4];
#pragma unroll
        for (int j = 0; j < 4; j++) {
            int e = base + j * 256;
            v[j] = e < E_;
            if (v[j]) load_sd(ei, is64, e, E_, sj[j], dj[j]);
        }
#pragma unroll
        for (int j = 0; j < 4; j++) {
            int e = base + j * 256;
            if (v[j]) {
                s16[e] = (unsigned short)sj[j];
                d16[e] = (unsigned short)dj[j];
            }
        }
#pragma unroll
        for (int j = 0; j < 4; j++) {
            if (v[j]) rj[j] = atomicAdd(deg + dj[j], 1);
        }
#pragma unroll
        for (int j = 0; j < 4; j++) {
            int e = base + j * 256;
            if (v[j]) r16[e] = (unsigned short)rj[j];
        }
        return;
    }

    // ---------------- gemm1 path (K=128, NOUT=32, A from fp32) -------------
    const int nb   = blockIdx.x * 64;
    const int wave = tid >> 6, lane = tid & 63;
    const int m16  = lane & 15, quad = lane >> 4;

    if (tid < 32) { As[tid] = att_s[tid]; Ad[tid] = att_d[tid]; }

    f32x4 acc[NT];
#pragma unroll
    for (int t = 0; t < NT; t++) acc[t] = (f32x4){0.f, 0.f, 0.f, 0.f};

    for (int kc = 0; kc < 128; kc += KC) {
        {
            int node = tid >> 2, seg = tid & 3;
            int gn = nb + node;
            f16x8 v = {0, 0, 0, 0, 0, 0, 0, 0};
            if (gn < n) {
                const float4* p = (const float4*)(x + (size_t)gn * 128 + kc + seg * 8);
                float4 a = p[0], b = p[1];
                v = (f16x8){(_Float16)a.x, (_Float16)a.y, (_Float16)a.z, (_Float16)a.w,
                            (_Float16)b.x, (_Float16)b.y, (_Float16)b.z, (_Float16)b.w};
            }
            *(f16x8*)&Xs[node * XP + seg * 8] = v;
        }
        if (tid < 32 * 4) {
            int col = tid >> 2, seg = tid & 3;
            *(f16x8*)&Ws[col * XP + seg * 8] =
                *(const f16x8*)(Wt1 + (size_t)col * 128 + kc + seg * 8);
        }
        __syncthreads();

        f16x8 a = *(const f16x8*)&Xs[(wave * 16 + m16) * XP + quad * 8];
#pragma unroll
        for (int t = 0; t < NT; t++) {
            f16x8 b = *(const f16x8*)&Ws[(t * 16 + m16) * XP + quad * 8];
            acc[t] = __builtin_amdgcn_mfma_f32_16x16x32_f16(a, b, acc[t], 0, 0, 0);
        }
        __syncthreads();
    }

#pragma unroll
    for (int t = 0; t < NT; t++) {
#pragma unroll
        for (int r = 0; r < 4; r++) {
            int row = wave * 16 + quad * 4 + r;
            Hs[row * HP + t * 16 + m16] = (_Float16)acc[t][r];
        }
    }
    __syncthreads();

    if (tid < 64 * 4) {
        int row = tid >> 2, seg = tid & 3;
        int gn = nb + row;
        if (gn < n)
            *(f16x8*)(h + (size_t)gn * 32 + seg * 8) =
                *(const f16x8*)&Hs[row * HP + seg * 8];
    }

    {
        int node = tid >> 2, head = tid & 3;
        int gn = nb + node;
        const _Float16* hr = &Hs[node * HP + head * C];
        float s1 = 0.f, s2 = 0.f;
#pragma unroll
        for (int c = 0; c < C; c++) {
            float v = (float)hr[c];
            s1 += v * As[head * C + c];
            s2 += v * Ad[head * C + c];
        }
        if (gn < n) {
            a_s[gn * 4 + head] = s1;
            a_d[gn * 4 + head] = s2;
        }
    }
}

// ---------------------------------------------------------------------------
// CSR scan + scatter (Round-12 structure).
// ---------------------------------------------------------------------------
__device__ __forceinline__ int wave_incl_scan(int v)
{
    int lane = threadIdx.x & 63;
#pragma unroll
    for (int off = 1; off < 64; off <<= 1) {
        int t = __shfl_up(v, off);
        if (lane >= off) v += t;
    }
    return v;
}

__global__ __launch_bounds__(1024) void scan_part_kernel(const int* __restrict__ deg,
                                                         int* __restrict__ start,
                                                         int* __restrict__ bsum, int n)
{
    __shared__ int wsum[16];
    int i = blockIdx.x * 1024 + threadIdx.x;
    int wid = threadIdx.x >> 6, lane = threadIdx.x & 63;
    int v = (i < n) ? deg[i] : 0;
    int incl = wave_incl_scan(v);
    if (lane == 63) wsum[wid] = incl;
    __syncthreads();
    if (wid == 0) {
        int w = (lane < 16) ? wsum[lane] : 0;
        w = wave_incl_scan(w);
        if (lane < 16) wsum[lane] = w;
    }
    __syncthreads();
    int excl = incl - v + (wid ? wsum[wid - 1] : 0);
    if (i < n) start[i] = excl;
    if (threadIdx.x == 1023) bsum[blockIdx.x] = wsum[15];
}

__global__ __launch_bounds__(1024) void scan_add_kernel(const int* __restrict__ deg,
                                                        const int* __restrict__ bsum,
                                                        int* __restrict__ start, int n)
{
    __shared__ int off_sh;
    if (threadIdx.x == 0) {
        int s = 0;
        for (int j = 0; j < blockIdx.x; j++) s += bsum[j];
        off_sh = s;
    }
    __syncthreads();
    int i = blockIdx.x * 1024 + threadIdx.x;
    if (i >= n) return;
    int v = start[i] + off_sh;
    start[i] = v;
    if (i == n - 1) start[n] = v + deg[i];
}

__global__ __launch_bounds__(256) void scatter_kernel(
    const unsigned short* __restrict__ s16, const unsigned short* __restrict__ d16,
    const unsigned short* __restrict__ r16, const int* __restrict__ start,
    unsigned short* __restrict__ sorted_src, int E_)
{
    int base = blockIdx.x * 1024 + threadIdx.x;
    int sj[4], dj[4], rj[4];
    bool v[4];
#pragma unroll
    for (int j = 0; j < 4; j++) {
        int e = base + j * 256;
        v[j] = e < E_;
        sj[j] = v[j] ? (int)s16[e] : 0;
        dj[j] = v[j] ? (int)d16[e] : 0;
        rj[j] = v[j] ? (int)r16[e] : 0;
    }
    int pj[4];
#pragma unroll
    for (int j = 0; j < 4; j++) {
        if (v[j]) pj[j] = start[dj[j]] + rj[j];
    }
#pragma unroll
    for (int j = 0; j < 4; j++) {
        if (v[j])
            __builtin_nontemporal_store((unsigned short)sj[j], sorted_src + pj[j]);
    }
}

// ---------------------------------------------------------------------------
// MFMA GEMM + fused attention epilogue (Round-10 structure, verified).
// Used standalone for layers 2/3 (A fp16 from the agg kernels).
// ---------------------------------------------------------------------------
template <int K, int NOUT>
__global__ __launch_bounds__(256) void gemm_mfma_kernel(
    const __half* __restrict__ xin, const __half* __restrict__ Wt,
    const float* __restrict__ att_s, const float* __restrict__ att_d,
    __half* __restrict__ h, float* __restrict__ a_s, float* __restrict__ a_d, int n)
{
    constexpr int KC = 32;
    constexpr int NT = NOUT / 16;
    constexpr int XP = KC + 8;
    constexpr int HP = NOUT + 8;
    constexpr int C  = NOUT / 4;

    __shared__ _Float16 Xs[64 * XP];
    __shared__ _Float16 Ws[NOUT * XP];
    __shared__ _Float16 Hs[64 * HP];
    __shared__ float As[NOUT], Ad[NOUT];

    const int tid  = threadIdx.x;
    const int nb   = blockIdx.x * 64;
    const int wave = tid >> 6, lane = tid & 63;
    const int m16  = lane & 15, quad = lane >> 4;

    if (tid < NOUT) { As[tid] = att_s[tid]; Ad[tid] = att_d[tid]; }

    f32x4 acc[NT];
#pragma unroll
    for (int t = 0; t < NT; t++) acc[t] = (f32x4){0.f, 0.f, 0.f, 0.f};

    for (int kc = 0; kc < K; kc += KC) {
        {
            int node = tid >> 2, seg = tid & 3;
            int gn = nb + node;
            f16x8 v = {0, 0, 0, 0, 0, 0, 0, 0};
            if (gn < n)
                v = *(const f16x8*)(xin + (size_t)gn * K + kc + seg * 8);
            *(f16x8*)&Xs[node * XP + seg * 8] = v;
        }
        for (int u = tid; u < NOUT * 4; u += 256) {
            int col = u >> 2, seg = u & 3;
            *(f16x8*)&Ws[col * XP + seg * 8] =
                *(const f16x8*)(Wt + (size_t)col * K + kc + seg * 8);
        }
        __syncthreads();

        f16x8 a = *(const f16x8*)&Xs[(wave * 16 + m16) * XP + quad * 8];
#pragma unroll
        for (int t = 0; t < NT; t++) {
            f16x8 b = *(const f16x8*)&Ws[(t * 16 + m16) * XP + quad * 8];
            acc[t] = __builtin_amdgcn_mfma_f32_16x16x32_f16(a, b, acc[t], 0, 0, 0);
        }
        __syncthreads();
    }

#pragma unroll
    for (int t = 0; t < NT; t++) {
#pragma unroll
        for (int r = 0; r < 4; r++) {
            int row = wave * 16 + quad * 4 + r;
            Hs[row * HP + t * 16 + m16] = (_Float16)acc[t][r];
        }
    }
    __syncthreads();

    for (int u = tid; u < 64 * NOUT / 8; u += 256) {
        int row = u / (NOUT / 8), seg = u % (NOUT / 8);
        int gn = nb + row;
        if (gn < n)
            *(f16x8*)(h + (size_t)gn * NOUT + seg * 8) =
                *(const f16x8*)&Hs[row * HP + seg * 8];
    }

    {
        int node = tid >> 2, head = tid & 3;
        int gn = nb + node;
        const _Float16* hr = &Hs[node * HP + head * C];
        float s1 = 0.f, s2 = 0.f;
#pragma unroll 4
        for (int c = 0; c < C; c++) {
            float v = (float)hr[c];
            s1 += v * As[head * C + c];
            s2 += v * Ad[head * C + c];
        }
        if (gn < n) {
            a_s[gn * 4 + head] = s1;
            a_d[gn * 4 + head] = s2;
        }
    }
}

// ---------------------------------------------------------------------------
// SINGLE-SWEEP fused softmax+aggregation, F = 128 (layers 2/3).
// 16 thr/node x 16 B loads, 16 nodes/block, 8-deep pipeline (Round-15 best).
// MODE 0: +bias, ELU -> fp16. MODE 1: head-mean, +bias -> fp32.
// ---------------------------------------------------------------------------
template <int MODE>
__global__ __launch_bounds__(256) void gat_agg128_kernel(
    const int* __restrict__ start, const unsigned short* __restrict__ ss,
    const __half* __restrict__ h, const float* __restrict__ a_s,
    const float* __restrict__ a_d, const float* __restrict__ bias,
    void* __restrict__ out, int n)
{
    int local = threadIdx.x >> 4;
    int q     = threadIdx.x & 15;
    int node  = blockIdx.x * 16 + local;
    bool active = node < n;
    int s0 = 0, s1 = 0;
    if (active) { s0 = start[node]; s1 = start[node + 1]; }
    int head = q >> 2;
    float adh = active ? a_d[node * 4 + head] : 0.f;
    const f16x8* __restrict__ h8 = (const f16x8*)h + q;

    float acc[8];
#pragma unroll
    for (int j = 0; j < 8; j++) acc[j] = 0.f;
    float sm = 0.f;

    int i = s0;
    for (; i + 8 <= s1; i += 8) {
        int   sj[8];
        float ej[8];
        h8u   rj[8];
#pragma unroll
        for (int j = 0; j < 8; j++) sj[j] = (int)ss[i + j];
#pragma unroll
        for (int j = 0; j < 8; j++) ej[j] = a_s[sj[j] * 4 + head];
#pragma unroll
        for (int j = 0; j < 8; j++) rj[j].v = h8[(size_t)sj[j] * 16];
#pragma unroll
        for (int j = 0; j < 8; j++) {
            float e = ej[j] + adh;
            e = e > 0.f ? e : NEG_SLOPE * e;
            float p = __expf(e);
            sm += p;
#pragma unroll
            for (int k = 0; k < 4; k++) {
                float2 f = __half22float2(rj[j].h2[k]);
                acc[2 * k]     += f.x * p;
                acc[2 * k + 1] += f.y * p;
            }
        }
    }
    for (; i < s1; i++) {
        int s = (int)ss[i];
        float e = a_s[s * 4 + head] + adh;
        e = e > 0.f ? e : NEG_SLOPE * e;
        float p = __expf(e);
        sm += p;
        h8u u; u.v = h8[(size_t)s * 16];
#pragma unroll
        for (int k = 0; k < 4; k++) {
            float2 f = __half22float2(u.h2[k]);
            acc[2 * k]     += f.x * p;
            acc[2 * k + 1] += f.y * p;
        }
    }

    float inv = 1.f / (sm + 1e-16f);
#pragma unroll
    for (int j = 0; j < 8; j++) acc[j] *= inv;

    if (MODE == 0) {
        if (active) {
            h8u u;
#pragma unroll
            for (int k = 0; k < 4; k++) {
                float vx = acc[2 * k]     + bias[q * 8 + 2 * k];
                float vy = acc[2 * k + 1] + bias[q * 8 + 2 * k + 1];
                vx = vx > 0.f ? vx : (__expf(vx) - 1.f);
                vy = vy > 0.f ? vy : (__expf(vy) - 1.f);
                u.h2[k] = __floats2half2_rn(vx, vy);
            }
            *(f16x8*)((__half*)out + (size_t)node * 128 + q * 8) = u.v;
        }
    } else {
        __shared__ float sh[16][132];
#pragma unroll
        for (int j = 0; j < 8; j++) sh[local][q * 8 + j] = acc[j];
        __syncthreads();
        if (q < 4 && active) {
            float r[8];
#pragma unroll
            for (int j = 0; j < 8; j++) {
                int c = q * 8 + j;
                r[j] = 0.25f * (sh[local][c] + sh[local][32 + c] + sh[local][64 + c] +
                                sh[local][96 + c]) + bias[c];
            }
            float4* o4 = (float4*)((float*)out + (size_t)node * 32 + q * 8);
            o4[0] = make_float4(r[0], r[1], r[2], r[3]);
            o4[1] = make_float4(r[4], r[5], r[6], r[7]);
        }
    }
}

// ---------------------------------------------------------------------------
// SINGLE-SWEEP fused softmax+aggregation, F = 32 (layer 1). 4 thr/node x
// 16 B loads, 64 nodes/block, 8-deep pipeline, fp16 out. head = q.
// ---------------------------------------------------------------------------
__global__ __launch_bounds__(256) void gat_agg32_kernel(
    const int* __restrict__ start, const unsigned short* __restrict__ ss,
    const __half* __restrict__ h, const float* __restrict__ a_s,
    const float* __restrict__ a_d, const float* __restrict__ bias,
    __half* __restrict__ out, int n)
{
    int local = threadIdx.x >> 2;
    int q     = threadIdx.x & 3;
    int node  = blockIdx.x * 64 + local;
    bool active = node < n;
    int s0 = 0, s1 = 0;
    if (active) { s0 = start[node]; s1 = start[node + 1]; }
    float adh = active ? a_d[node * 4 + q] : 0.f;
    const f16x8* __restrict__ h8 = (const f16x8*)h + q;

    float acc[8];
#pragma unroll
    for (int j = 0; j < 8; j++) acc[j] = 0.f;
    float sm = 0.f;

    int i = s0;
    for (; i + 8 <= s1; i += 8) {
        int   sj[8];
        float ej[8];
        h8u   rj[8];
#pragma unroll
        for (int j = 0; j < 8; j++) sj[j] = (int)ss[i + j];
#pragma unroll
        for (int j = 0; j < 8; j++) ej[j] = a_s[sj[j] * 4 + q];
#pragma unroll
        for (int j = 0; j < 8; j++) rj[j].v = h8[(size_t)sj[j] * 4];
#pragma unroll
        for (int j = 0; j < 8; j++) {
            float e = ej[j] + adh;
            e = e > 0.f ? e : NEG_SLOPE * e;
            float p = __expf(e);
            sm += p;
#pragma unroll
            for (int k = 0; k < 4; k++) {
                float2 f = __half22float2(rj[j].h2[k]);
                acc[2 * k]     += f.x * p;
                acc[2 * k + 1] += f.y * p;
            }
        }
    }
    for (; i < s1; i++) {
        int s = (int)ss[i];
        float e = a_s[s * 4 + q] + adh;
        e = e > 0.f ? e : NEG_SLOPE * e;
        float p = __expf(e);
        sm += p;
        h8u u; u.v = h8[(size_t)s * 4];
#pragma unroll
        for (int k = 0; k < 4; k++) {
            float2 f = __half22float2(u.h2[k]);
            acc[2 * k]     += f.x * p;
            acc[2 * k + 1] += f.y * p;
        }
    }

    if (active) {
        float inv = 1.f / (sm + 1e-16f);
        h8u u;
#pragma unroll
        for (int k = 0; k < 4; k++) {
            float vx = acc[2 * k] * inv     + bias[q * 8 + 2 * k];
            float vy = acc[2 * k + 1] * inv + bias[q * 8 + 2 * k + 1];
            vx = vx > 0.f ? vx : (__expf(vx) - 1.f);
            vy = vy > 0.f ? vy : (__expf(vy) - 1.f);
            u.h2[k] = __floats2half2_rn(vx, vy);
        }
        *(f16x8*)(out + (size_t)node * 32 + q * 8) = u.v;
    }
}

// ---------------------------------------------------------------------------

extern "C" void kernel_launch(void* const* d_in, const int* in_sizes, int n_in,
                              void* d_out, int out_size, void* d_ws, size_t ws_size,
                              hipStream_t stream)
{
    const float* x   = (const float*)d_in[0];
    const void*  ei  = d_in[1];
    const float* W1  = (const float*)d_in[2];
    const float* as1 = (const float*)d_in[3];
    const float* ad1 = (const float*)d_in[4];
    const float* b1  = (const float*)d_in[5];
    const float* W2  = (const float*)d_in[6];
    const float* as2 = (const float*)d_in[7];
    const float* ad2 = (const float*)d_in[8];
    const float* b2  = (const float*)d_in[9];
    const float* W3  = (const float*)d_in[10];
    const float* as3 = (const float*)d_in[11];
    const float* ad3 = (const float*)d_in[12];
    const float* b3  = (const float*)d_in[13];
    float* out = (float*)d_out;

    const int N_ = in_sizes[0] / 128;
    const int E_ = in_sizes[1] / 2;

    char* ws = (char*)d_ws;
    size_t off = 0;
    auto alloc = [&](size_t nbytes) -> void* {
        void* p = ws + off;
        off += (nbytes + 255) & ~(size_t)255;
        return p;
    };
    __half* h          = (__half*)alloc((size_t)N_ * 128 * 2);
    __half* x2h        = (__half*)alloc((size_t)N_ * 32 * 2);
    __half* x3h        = (__half*)alloc((size_t)N_ * 128 * 2);
    __half* Wt1        = (__half*)alloc(128 * 32 * 2);
    __half* Wt2        = (__half*)alloc(32 * 128 * 2);
    __half* Wt3        = (__half*)alloc(128 * 128 * 2);
    float* asrc        = (float*)alloc((size_t)N_ * 4 * 4);
    float* adst        = (float*)alloc((size_t)N_ * 4 * 4);
    int*   deg         = (int*)alloc((size_t)N_ * 4);
    int*   start       = (int*)alloc((size_t)(N_ + 1) * 4);
    unsigned short* sorted_src = (unsigned short*)alloc((size_t)E_ * 2);
    unsigned short* s16        = (unsigned short*)alloc((size_t)E_ * 2);
    unsigned short* d16        = (unsigned short*)alloc((size_t)E_ * 2);
    unsigned short* r16        = (unsigned short*)alloc((size_t)E_ * 2);
    int*   bsum        = (int*)alloc(4096);
    int*   flag        = (int*)alloc(256);

    const int gN16  = cdiv(N_, 16);
    const int gN64  = cdiv(N_, 64);
    const int gHist = cdiv(E_, 1024);
    const int nSB   = cdiv(N_, 1024);
    int prepWork = N_ > 128 * 128 ? N_ : 128 * 128;

    // ---- Prep, then [gemm1 || hist] in one dispatch, then scan+scatter ----
    prep_kernel<<<cdiv(prepWork, 256), 256, 0, stream>>>(ei, E_, N_, flag, deg,
                                                         W1, Wt1, W2, Wt2, W3, Wt3);
    gemm1_hist_kernel<<<gN64 + gHist, 256, 0, stream>>>(
        x, Wt1, as1, ad1, h, asrc, adst, N_, gN64,
        ei, flag, deg, s16, d16, r16, E_);
    scan_part_kernel<<<nSB, 1024, 0, stream>>>(deg, start, bsum, N_);
    scan_add_kernel<<<nSB, 1024, 0, stream>>>(deg, bsum, start, N_);
    scatter_kernel<<<cdiv(E_, 1024), 256, 0, stream>>>(s16, d16, r16, start,
                                                       sorted_src, E_);

    // ---- Layer 1 agg ----
    gat_agg32_kernel<<<gN64, 256, 0, stream>>>(start, sorted_src, h, asrc, adst, b1,
                                               x2h, N_);

    // ---- Layer 2: gemm + agg ----
    gemm_mfma_kernel<32, 128><<<gN64, 256, 0, stream>>>(x2h, Wt2, as2, ad2, h,
                                                        asrc, adst, N_);
    gat_agg128_kernel<0><<<gN16, 256, 0, stream>>>(start, sorted_src, h, asrc, adst, b2,
                                                   x3h, N_);

    // ---- Layer 3: gemm + final agg ----
    gemm_mfma_kernel<128, 128><<<gN64, 256, 0, stream>>>(x3h, Wt3, as3, ad3, h,
                                                         asrc, adst, N_);
    gat_agg128_kernel<1><<<gN16, 256, 0, stream>>>(start, sorted_src, h, asrc, adst, b3,
                                                   out, N_);
}